// Round 20
// baseline (114.170 us; speedup 1.0000x reference)
//
#include <hip/hip_runtime.h>

#define LSEQ 4096
#define EMB  1024
#define NH   16
#define HD   64

typedef __attribute__((ext_vector_type(8)))  __bf16 bf16x8;
typedef __attribute__((ext_vector_type(4)))  float f32x4;
typedef __attribute__((ext_vector_type(16))) float f32x16;
typedef __attribute__((ext_vector_type(8)))  unsigned short u16x8;
typedef __attribute__((ext_vector_type(4)))  unsigned short u16x4;
typedef __attribute__((ext_vector_type(4)))  unsigned int u32x4;

__device__ __forceinline__ unsigned short f2bf(float f) {
    union { float f; unsigned u; } v; v.f = f;
    unsigned r = v.u + 0x7fffu + ((v.u >> 16) & 1u);
    return (unsigned short)(r >> 16);
}

__device__ __forceinline__ unsigned cvt_pk_bf16(float a, float b) {
    unsigned r;
    asm("v_cvt_pk_bf16_f32 %0, %1, %2" : "=v"(r) : "v"(a), "v"(b));
    return r;
}

// exchange: x'[0:31]=x, x'[32:63]=y[l-32]; y'[0:31]=x[l+32], y'[32:63]=y
__device__ __forceinline__ void plswap(unsigned &x, unsigned &y) {
    asm volatile("v_permlane32_swap_b32 %0, %1" : "+v"(x), "+v"(y));
}

__device__ __forceinline__ f32x4 mfma16(u16x8 a, u16x8 b, f32x4 c) {
    return __builtin_amdgcn_mfma_f32_16x16x32_bf16(
        __builtin_bit_cast(bf16x8, a), __builtin_bit_cast(bf16x8, b), c, 0, 0, 0);
}

__device__ __forceinline__ f32x16 mfma32(u16x8 a, u16x8 b, f32x16 c) {
    return __builtin_amdgcn_mfma_f32_32x32x16_bf16(
        __builtin_bit_cast(bf16x8, a), __builtin_bit_cast(bf16x8, b), c, 0, 0, 0);
}

__device__ __forceinline__ void gload16(const void* g, void* l) {
    __builtin_amdgcn_global_load_lds((const __attribute__((address_space(1))) unsigned int*)g,
                                     (__attribute__((address_space(3))) unsigned int*)l,
                                     16, 0, 0);
}

// ---------------- fused fp32 -> bf16 convert ----------------
#define NXC (LSEQ * EMB / 4)
#define NAC (3 * EMB * EMB / 4)
#define NPC (EMB * EMB / 4)
__global__ __launch_bounds__(256) void cvt_all(const float* __restrict__ x,
                                               const float* __restrict__ wa,
                                               const float* __restrict__ wp,
                                               unsigned short* __restrict__ out) {
    int i = blockIdx.x * 256 + threadIdx.x;
    if (i >= NXC + NAC + NPC) return;
    const float* src;
    if (i < NXC)             src = x + (size_t)i * 4;
    else if (i < NXC + NAC)  src = wa + (size_t)(i - NXC) * 4;
    else                     src = wp + (size_t)(i - NXC - NAC) * 4;
    f32x4 v = *(const f32x4*)src;
    u16x4 o;
    o[0] = f2bf(v[0]); o[1] = f2bf(v[1]); o[2] = f2bf(v[2]); o[3] = f2bf(v[3]);
    *(u16x4*)(out + (size_t)i * 4) = o;
}

// ---------------- QKV GEMM: 128x128, BK=32 (m97-matched point) ----------------
// BK=32: 64B rows are naturally conflict-free for b128 frag reads (2 lanes/bank-group,
// free per m136) -> no swizzle; staging is fully linear+coalesced. LDS 16KB, 3 blocks/CU.
__global__ __launch_bounds__(256, 3) void gemm_qkv(const unsigned short* __restrict__ A,
                                                   const unsigned short* __restrict__ B,
                                                   unsigned short* __restrict__ Qo,
                                                   unsigned short* __restrict__ Ko,
                                                   unsigned short* __restrict__ Vto) {
    __shared__ unsigned short As[128 * 32];
    __shared__ unsigned short Bs[128 * 32];
    const int d0 = blockIdx.x;
    const int wg = (d0 & 7) * 96 + (d0 >> 3);   // bijective XCD grouping
    const int bx = wg % 24, by = wg / 24;
    const int tid = threadIdx.x;
    const int lane = tid & 63;
    const int wv = tid >> 6;
    const int wm = wv >> 1, wn = wv & 1;
    const int li = lane & 15, g = lane >> 4;
    const int m0 = by * 128, n0 = bx * 128;
    f32x4 acc[4][4] = {};
    for (int k0 = 0; k0 < EMB; k0 += 32) {
        #pragma unroll
        for (int i = 0; i < 2; ++i) {
            const int o = i * 4096 + tid * 16;          // linear dest, 64B rows
            const int r = o >> 6, cb = o & 63;
            gload16((const char*)A + ((size_t)(m0 + r) * EMB + k0) * 2 + cb, (char*)As + o);
            gload16((const char*)B + ((size_t)(n0 + r) * EMB + k0) * 2 + cb, (char*)Bs + o);
        }
        __syncthreads();
        u16x8 af[4], bfr[4];
        #pragma unroll
        for (int mb = 0; mb < 4; ++mb)
            af[mb] = *(const u16x8*)(As + (wm * 64 + mb * 16 + li) * 32 + g * 8);
        #pragma unroll
        for (int nb = 0; nb < 4; ++nb)
            bfr[nb] = *(const u16x8*)(Bs + (wn * 64 + nb * 16 + li) * 32 + g * 8);
        #pragma unroll
        for (int mb = 0; mb < 4; ++mb)
            #pragma unroll
            for (int nb = 0; nb < 4; ++nb)
                acc[mb][nb] = mfma16(af[mb], bfr[nb], acc[mb][nb]);
        __syncthreads();
    }
    if (n0 < EMB) {
        for (int mb = 0; mb < 4; ++mb)
            for (int nb = 0; nb < 4; ++nb)
                for (int r = 0; r < 4; ++r) {
                    const int m = m0 + wm * 64 + mb * 16 + g * 4 + r;
                    const int n = n0 + wn * 64 + nb * 16 + li;
                    Qo[((size_t)(n >> 6) * LSEQ + m) * HD + (n & 63)] =
                        f2bf(acc[mb][nb][r] * 0.1803368801111244f);
                }
    } else if (n0 < 2 * EMB) {
        for (int mb = 0; mb < 4; ++mb)
            for (int nb = 0; nb < 4; ++nb)
                for (int r = 0; r < 4; ++r) {
                    const int m = m0 + wm * 64 + mb * 16 + g * 4 + r;
                    const int c = n0 - EMB + wn * 64 + nb * 16 + li;
                    Ko[((size_t)(c >> 6) * LSEQ + m) * HD + (c & 63)] = f2bf(acc[mb][nb][r]);
                }
    } else {
        for (int mb = 0; mb < 4; ++mb)
            for (int nb = 0; nb < 4; ++nb) {
                const int mbase = m0 + wm * 64 + mb * 16 + g * 4;
                const int c = n0 - 2 * EMB + wn * 64 + nb * 16 + li;
                u16x4 pv;
                pv[0] = f2bf(acc[mb][nb][0]);
                pv[1] = f2bf(acc[mb][nb][1]);
                pv[2] = f2bf(acc[mb][nb][2]);
                pv[3] = f2bf(acc[mb][nb][3]);
                *(u16x4*)(Vto + ((size_t)(c >> 6) * HD + (c & 63)) * LSEQ + mbase) = pv;
            }
    }
}

// ---------------- flash attention (causal): KV-parity wave split (R13/R14/R18/R19 verbatim) ----------------
__global__ __launch_bounds__(512, 4) void attn_fwd(const unsigned short* __restrict__ Q,
                                                   const unsigned short* __restrict__ K,
                                                   const unsigned short* __restrict__ Vt,
                                                   unsigned short* __restrict__ Y) {
    __shared__ char LB[2][32768];
    const int d0 = blockIdx.x;
    const int grp = d0 & 255;
    const int head = 2 * (grp & 7) + ((grp >> 3) & 1);
    const int t16 = grp >> 4;
    const int s = (d0 < 256) ? (31 - t16) : t16;
    const int tid = threadIdx.x, lane = tid & 63, w = tid >> 6;
    const int qs = w & 3, par = w >> 2;
    const int li = lane & 31, hf = lane >> 5;
    const int qw0 = s * 128 + qs * 32;
    const int qrow = qw0 + li;
    const int jmaxw = 2 * s + (qs >> 1);
    const int nst = s + 1;
    const char* KhB = (const char*)(K + (size_t)head * LSEQ * HD);
    const char* VhB = (const char*)(Vt + (size_t)head * HD * LSEQ);

    u16x8 bq[4];
    #pragma unroll
    for (int ks = 0; ks < 4; ++ks)
        bq[ks] = *(const u16x8*)(Q + ((size_t)head * LSEQ + qrow) * HD + ks * 16 + hf * 8);

    int off[4];
    #pragma unroll
    for (int ks = 0; ks < 4; ++ks) {
        const int c = 2 * ks + hf;
        off[ks] = c * 1024 + (((li & 24) | ((li & 7) ^ c)) << 4);
    }

    const int row0 = (tid >> 3) & 31, sch = tid & 7, half = tid >> 8;
    const int wd0 = sch * 1024 + (((row0 & 24) | ((row0 & 7) ^ sch)) << 4);

    u16x8 kr0, kr1, vr0, vr1;
    #define LOADKV(js_) do {                                                              \
        const char* kp_ = KhB + ((size_t)((js_) * 128 + half * 64 + row0)) * 128 + sch * 16; \
        const char* vp_ = VhB + (size_t)row0 * (LSEQ * 2) + ((js_) * 128 + half * 64) * 2 + sch * 16; \
        kr0 = *(const u16x8*)kp_;                                                         \
        kr1 = *(const u16x8*)(kp_ + 32 * 128);                                            \
        vr0 = *(const u16x8*)vp_;                                                         \
        vr1 = *(const u16x8*)(vp_ + (size_t)32 * (LSEQ * 2));                             \
    } while (0)
    #define WRITEKV(b_) do {                                                              \
        char* base_ = LB[b_] + half * 8192;                                               \
        *(u16x8*)(base_ + wd0)               = kr0;                                       \
        *(u16x8*)(base_ + wd0 + 512)         = kr1;                                       \
        *(u16x8*)(base_ + 16384 + wd0)       = vr0;                                       \
        *(u16x8*)(base_ + 16384 + wd0 + 512) = vr1;                                       \
    } while (0)

    float l_i = 0.f;
    f32x16 oA = {}, oB = {};

    LOADKV(0);
    WRITEKV(0);
    __syncthreads();
    for (int js = 0; js < nst; ++js) {
        const int cur = js & 1;
        if (js + 1 < nst) LOADKV(js + 1);
        const int j = 2 * js + par;
        if (j <= jmaxw) {
            const char* Kb = LB[cur] + par * 8192;
            const char* Vb = LB[cur] + 16384 + par * 8192;
            f32x16 sA = {}, sB = {};
            __builtin_amdgcn_s_setprio(1);
            #pragma unroll
            for (int ks = 0; ks < 4; ++ks) {
                const u16x8 ka0 = *(const u16x8*)(Kb + off[ks]);
                const u16x8 ka1 = *(const u16x8*)(Kb + off[ks] + 512);
                sA = mfma32(ka0, bq[ks], sA);
                sB = mfma32(ka1, bq[ks], sB);
            }
            __builtin_amdgcn_s_setprio(0);
            if (j == jmaxw && (j * 64 + 63 > qw0)) {
                const int kbase = j * 64;
                #pragma unroll
                for (int r = 0; r < 16; ++r) {
                    const int kvl = kbase + (r & 3) + 8 * (r >> 2) + 4 * hf;
                    if (kvl > qrow)      sA[r] = -1e30f;
                    if (kvl + 32 > qrow) sB[r] = -1e30f;
                }
            }
            float s0 = 0.f, s1 = 0.f;
            unsigned uA[8], uB[8];
            #pragma unroll
            for (int wd = 0; wd < 8; ++wd) {
                const float a0 = __builtin_amdgcn_exp2f(sA[2 * wd]);
                const float a1 = __builtin_amdgcn_exp2f(sA[2 * wd + 1]);
                const float b0 = __builtin_amdgcn_exp2f(sB[2 * wd]);
                const float b1 = __builtin_amdgcn_exp2f(sB[2 * wd + 1]);
                s0 += a0 + a1; s1 += b0 + b1;
                uA[wd] = cvt_pk_bf16(a0, a1);
                uB[wd] = cvt_pk_bf16(b0, b1);
            }
            l_i += s0 + s1;
            plswap(uA[0], uA[2]); plswap(uA[1], uA[3]);
            plswap(uA[4], uA[6]); plswap(uA[5], uA[7]);
            plswap(uB[0], uB[2]); plswap(uB[1], uB[3]);
            plswap(uB[4], uB[6]); plswap(uB[5], uB[7]);
            const u32x4 wA0 = {uA[0], uA[1], uA[2], uA[3]};
            const u32x4 wA1 = {uA[4], uA[5], uA[6], uA[7]};
            const u32x4 wB0 = {uB[0], uB[1], uB[2], uB[3]};
            const u32x4 wB1 = {uB[4], uB[5], uB[6], uB[7]};
            const u16x8 ap0 = __builtin_bit_cast(u16x8, wA0);
            const u16x8 ap1 = __builtin_bit_cast(u16x8, wA1);
            const u16x8 ap2 = __builtin_bit_cast(u16x8, wB0);
            const u16x8 ap3 = __builtin_bit_cast(u16x8, wB1);
            const u16x8 va0 = *(const u16x8*)(Vb + off[0]);
            const u16x8 va1 = *(const u16x8*)(Vb + off[1]);
            const u16x8 va2 = *(const u16x8*)(Vb + off[2]);
            const u16x8 va3 = *(const u16x8*)(Vb + off[3]);
            const u16x8 vc0 = *(const u16x8*)(Vb + off[0] + 512);
            const u16x8 vc1 = *(const u16x8*)(Vb + off[1] + 512);
            const u16x8 vc2 = *(const u16x8*)(Vb + off[2] + 512);
            const u16x8 vc3 = *(const u16x8*)(Vb + off[3] + 512);
            __builtin_amdgcn_s_setprio(1);
            oA = mfma32(ap0, va0, oA);
            oA = mfma32(ap1, va1, oA);
            oA = mfma32(ap2, va2, oA);
            oA = mfma32(ap3, va3, oA);
            oB = mfma32(ap0, vc0, oB);
            oB = mfma32(ap1, vc1, oB);
            oB = mfma32(ap2, vc2, oB);
            oB = mfma32(ap3, vc3, oB);
            __builtin_amdgcn_s_setprio(0);
        }
        if (js + 1 < nst) WRITEKV(cur ^ 1);
        __syncthreads();
    }
    #undef LOADKV
    #undef WRITEKV
    if (par == 1) {
        float* po = (float*)(LB[0] + qs * 8192);
        #pragma unroll
        for (int r = 0; r < 16; ++r) {
            po[r * 64 + lane]        = oA[r];
            po[(16 + r) * 64 + lane] = oB[r];
        }
        ((float*)LB[1])[qs * 64 + lane] = l_i;
    }
    __syncthreads();
    if (par == 0) {
        const float* po = (const float*)(LB[0] + qs * 8192);
        l_i += ((const float*)LB[1])[qs * 64 + lane];
        #pragma unroll
        for (int r = 0; r < 16; ++r) {
            oA[r] += po[r * 64 + lane];
            oB[r] += po[(16 + r) * 64 + lane];
        }
        const float lt = l_i + __shfl_xor(l_i, 32);
        const float linv = 1.0f / lt;
        #pragma unroll
        for (int r = 0; r < 16; ++r) {
            const int ql = (r & 3) + 8 * (r >> 2) + 4 * hf;
            const float gl = __shfl(linv, ql);
            Y[(size_t)(qw0 + ql) * EMB + head * HD + li]      = f2bf(oA[r] * gl);
            Y[(size_t)(qw0 + ql) * EMB + head * HD + 32 + li] = f2bf(oB[r] * gl);
        }
    }
}

// ---------------- proj GEMM: 64x128 tile, BK=64, swizzled (R19 verbatim) ----------------
__global__ __launch_bounds__(256, 4) void gemm_proj(const unsigned short* __restrict__ A,
                                                    const unsigned short* __restrict__ B,
                                                    float* __restrict__ C) {
    __shared__ unsigned short As[64 * 64];
    __shared__ unsigned short Bs[128 * 64];
    const int d0 = blockIdx.x;
    const int xcd = d0 & 7, i0 = d0 >> 3;
    const int by = xcd * 8 + i0 / 8;
    const int bx = i0 % 8;
    const int tid = threadIdx.x;
    const int lane = tid & 63;
    const int wv = tid >> 6;
    const int wm = wv >> 1, wn = wv & 1;
    const int li = lane & 15, g = lane >> 4;
    const int m0 = by * 64, n0 = bx * 128;
    f32x4 acc[2][4] = {};
    for (int k0 = 0; k0 < EMB; k0 += 64) {
        #pragma unroll
        for (int i = 0; i < 2; ++i) {
            const int o = i * 4096 + tid * 16;
            const int r = o >> 7, sl = (o >> 4) & 7, sc = (sl ^ (r & 7)) << 4;
            gload16((const char*)A + ((size_t)(m0 + r) * EMB + k0) * 2 + sc, (char*)As + o);
        }
        #pragma unroll
        for (int i = 0; i < 4; ++i) {
            const int o = i * 4096 + tid * 16;
            const int r = o >> 7, sl = (o >> 4) & 7, sc = (sl ^ (r & 7)) << 4;
            gload16((const char*)B + ((size_t)(n0 + r) * EMB + k0) * 2 + sc, (char*)Bs + o);
        }
        __syncthreads();
        #pragma unroll
        for (int h = 0; h < 2; ++h) {
            u16x8 af[2], bfr[4];
            #pragma unroll
            for (int mb = 0; mb < 2; ++mb) {
                const int row = wm * 32 + mb * 16 + li;
                const int c = h * 4 + g;
                af[mb] = *(const u16x8*)((const char*)As + row * 128 + ((c ^ (row & 7)) << 4));
            }
            #pragma unroll
            for (int nb = 0; nb < 4; ++nb) {
                const int row = wn * 64 + nb * 16 + li;
                const int c = h * 4 + g;
                bfr[nb] = *(const u16x8*)((const char*)Bs + row * 128 + ((c ^ (row & 7)) << 4));
            }
            #pragma unroll
            for (int mb = 0; mb < 2; ++mb)
                #pragma unroll
                for (int nb = 0; nb < 4; ++nb)
                    acc[mb][nb] = mfma16(af[mb], bfr[nb], acc[mb][nb]);
        }
        __syncthreads();
    }
    for (int mb = 0; mb < 2; ++mb)
        for (int nb = 0; nb < 4; ++nb)
            for (int r = 0; r < 4; ++r) {
                const int m = m0 + wm * 32 + mb * 16 + g * 4 + r;
                const int n = n0 + wn * 64 + nb * 16 + li;
                C[(size_t)m * EMB + n] = acc[mb][nb][r];
            }
}

extern "C" void kernel_launch(void* const* d_in, const int* in_sizes, int n_in,
                              void* d_out, int out_size, void* d_ws, size_t ws_size,
                              hipStream_t stream) {
    const float* x      = (const float*)d_in[0];
    const float* w_attn = (const float*)d_in[1];
    const float* w_proj = (const float*)d_in[2];
    float* out = (float*)d_out;

    unsigned short* ws  = (unsigned short*)d_ws;
    unsigned short* xb  = ws;
    unsigned short* wab = xb + (size_t)LSEQ * EMB;
    unsigned short* wpb = wab + (size_t)3 * EMB * EMB;
    unsigned short* Qb  = wpb + (size_t)EMB * EMB;
    unsigned short* Kb  = Qb + (size_t)LSEQ * EMB;
    unsigned short* Vtb = Kb + (size_t)LSEQ * EMB;
    unsigned short* Yb  = Vtb + (size_t)LSEQ * EMB;

    const int ntot = NXC + NAC + NPC;
    cvt_all<<<(ntot + 255) / 256, 256, 0, stream>>>(x, w_attn, w_proj, xb);
    gemm_qkv<<<dim3(768), 256, 0, stream>>>(xb, wab, Qb, Kb, Vtb);
    attn_fwd<<<dim3(512), 512, 0, stream>>>(Qb, Kb, Vtb, Yb);
    gemm_proj<<<dim3(512), 256, 0, stream>>>(Yb, wpb, out);
}

// Round 21
// 109.699 us; speedup vs baseline: 1.0408x; 1.0408x over previous
//
#include <hip/hip_runtime.h>

#define LSEQ 4096
#define EMB  1024
#define NH   16
#define HD   64

typedef __attribute__((ext_vector_type(8)))  __bf16 bf16x8;
typedef __attribute__((ext_vector_type(4)))  float f32x4;
typedef __attribute__((ext_vector_type(16))) float f32x16;
typedef __attribute__((ext_vector_type(8)))  unsigned short u16x8;
typedef __attribute__((ext_vector_type(4)))  unsigned short u16x4;
typedef __attribute__((ext_vector_type(4)))  unsigned int u32x4;

__device__ __forceinline__ unsigned short f2bf(float f) {
    union { float f; unsigned u; } v; v.f = f;
    unsigned r = v.u + 0x7fffu + ((v.u >> 16) & 1u);
    return (unsigned short)(r >> 16);
}

__device__ __forceinline__ unsigned cvt_pk_bf16(float a, float b) {
    unsigned r;
    asm("v_cvt_pk_bf16_f32 %0, %1, %2" : "=v"(r) : "v"(a), "v"(b));
    return r;
}

// exchange: x'[0:31]=x, x'[32:63]=y[l-32]; y'[0:31]=x[l+32], y'[32:63]=y
__device__ __forceinline__ void plswap(unsigned &x, unsigned &y) {
    asm volatile("v_permlane32_swap_b32 %0, %1" : "+v"(x), "+v"(y));
}

__device__ __forceinline__ f32x4 mfma16(u16x8 a, u16x8 b, f32x4 c) {
    return __builtin_amdgcn_mfma_f32_16x16x32_bf16(
        __builtin_bit_cast(bf16x8, a), __builtin_bit_cast(bf16x8, b), c, 0, 0, 0);
}

__device__ __forceinline__ f32x16 mfma32(u16x8 a, u16x8 b, f32x16 c) {
    return __builtin_amdgcn_mfma_f32_32x32x16_bf16(
        __builtin_bit_cast(bf16x8, a), __builtin_bit_cast(bf16x8, b), c, 0, 0, 0);
}

__device__ __forceinline__ void gload16(const void* g, void* l) {
    __builtin_amdgcn_global_load_lds((const __attribute__((address_space(1))) unsigned int*)g,
                                     (__attribute__((address_space(3))) unsigned int*)l,
                                     16, 0, 0);
}

// ---------------- fused fp32 -> bf16 convert ----------------
#define NXC (LSEQ * EMB / 4)
#define NAC (3 * EMB * EMB / 4)
#define NPC (EMB * EMB / 4)
__global__ __launch_bounds__(256) void cvt_all(const float* __restrict__ x,
                                               const float* __restrict__ wa,
                                               const float* __restrict__ wp,
                                               unsigned short* __restrict__ out) {
    int i = blockIdx.x * 256 + threadIdx.x;
    if (i >= NXC + NAC + NPC) return;
    const float* src;
    if (i < NXC)             src = x + (size_t)i * 4;
    else if (i < NXC + NAC)  src = wa + (size_t)(i - NXC) * 4;
    else                     src = wp + (size_t)(i - NXC - NAC) * 4;
    f32x4 v = *(const f32x4*)src;
    u16x4 o;
    o[0] = f2bf(v[0]); o[1] = f2bf(v[1]); o[2] = f2bf(v[2]); o[3] = f2bf(v[3]);
    *(u16x4*)(out + (size_t)i * 4) = o;
}

// ---------------- QKV GEMM: 128x128, BK=64, swizzled LDS (R19 verbatim — measured best) ----------------
__global__ __launch_bounds__(256, 3) void gemm_qkv(const unsigned short* __restrict__ A,
                                                   const unsigned short* __restrict__ B,
                                                   unsigned short* __restrict__ Qo,
                                                   unsigned short* __restrict__ Ko,
                                                   unsigned short* __restrict__ Vto) {
    __shared__ unsigned short As[128 * 64];
    __shared__ unsigned short Bs[128 * 64];
    const int d0 = blockIdx.x;
    const int wg = (d0 & 7) * 96 + (d0 >> 3);   // bijective XCD grouping
    const int bx = wg % 24, by = wg / 24;
    const int tid = threadIdx.x;
    const int lane = tid & 63;
    const int wv = tid >> 6;
    const int wm = wv >> 1, wn = wv & 1;
    const int li = lane & 15, g = lane >> 4;
    const int m0 = by * 128, n0 = bx * 128;
    f32x4 acc[4][4] = {};
    for (int k0 = 0; k0 < EMB; k0 += 64) {
        #pragma unroll
        for (int i = 0; i < 4; ++i) {
            const int o = i * 4096 + tid * 16;
            const int r = o >> 7, sl = (o >> 4) & 7, sc = (sl ^ (r & 7)) << 4;
            gload16((const char*)A + ((size_t)(m0 + r) * EMB + k0) * 2 + sc, (char*)As + o);
            gload16((const char*)B + ((size_t)(n0 + r) * EMB + k0) * 2 + sc, (char*)Bs + o);
        }
        __syncthreads();
        #pragma unroll
        for (int h = 0; h < 2; ++h) {
            u16x8 af[4], bfr[4];
            #pragma unroll
            for (int mb = 0; mb < 4; ++mb) {
                const int row = wm * 64 + mb * 16 + li;
                const int c = h * 4 + g;
                af[mb] = *(const u16x8*)((const char*)As + row * 128 + (((c ^ (row & 7))) << 4));
            }
            #pragma unroll
            for (int nb = 0; nb < 4; ++nb) {
                const int row = wn * 64 + nb * 16 + li;
                const int c = h * 4 + g;
                bfr[nb] = *(const u16x8*)((const char*)Bs + row * 128 + (((c ^ (row & 7))) << 4));
            }
            #pragma unroll
            for (int mb = 0; mb < 4; ++mb)
                #pragma unroll
                for (int nb = 0; nb < 4; ++nb)
                    acc[mb][nb] = mfma16(af[mb], bfr[nb], acc[mb][nb]);
        }
        __syncthreads();
    }
    if (n0 < EMB) {
        for (int mb = 0; mb < 4; ++mb)
            for (int nb = 0; nb < 4; ++nb)
                for (int r = 0; r < 4; ++r) {
                    const int m = m0 + wm * 64 + mb * 16 + g * 4 + r;
                    const int n = n0 + wn * 64 + nb * 16 + li;
                    Qo[((size_t)(n >> 6) * LSEQ + m) * HD + (n & 63)] =
                        f2bf(acc[mb][nb][r] * 0.1803368801111244f);
                }
    } else if (n0 < 2 * EMB) {
        for (int mb = 0; mb < 4; ++mb)
            for (int nb = 0; nb < 4; ++nb)
                for (int r = 0; r < 4; ++r) {
                    const int m = m0 + wm * 64 + mb * 16 + g * 4 + r;
                    const int c = n0 - EMB + wn * 64 + nb * 16 + li;
                    Ko[((size_t)(c >> 6) * LSEQ + m) * HD + (c & 63)] = f2bf(acc[mb][nb][r]);
                }
    } else {
        for (int mb = 0; mb < 4; ++mb)
            for (int nb = 0; nb < 4; ++nb) {
                const int mbase = m0 + wm * 64 + mb * 16 + g * 4;
                const int c = n0 - 2 * EMB + wn * 64 + nb * 16 + li;
                u16x4 pv;
                pv[0] = f2bf(acc[mb][nb][0]);
                pv[1] = f2bf(acc[mb][nb][1]);
                pv[2] = f2bf(acc[mb][nb][2]);
                pv[3] = f2bf(acc[mb][nb][3]);
                *(u16x4*)(Vto + ((size_t)(c >> 6) * HD + (c & 63)) * LSEQ + mbase) = pv;
            }
    }
}

// ---------------- flash attention (causal): KV-parity wave split (R13 structure — measured best) ----------------
__global__ __launch_bounds__(512, 4) void attn_fwd(const unsigned short* __restrict__ Q,
                                                   const unsigned short* __restrict__ K,
                                                   const unsigned short* __restrict__ Vt,
                                                   unsigned short* __restrict__ Y) {
    __shared__ char LB[2][32768];
    const int d0 = blockIdx.x;
    const int grp = d0 & 255;
    const int head = 2 * (grp & 7) + ((grp >> 3) & 1);
    const int t16 = grp >> 4;
    const int s = (d0 < 256) ? (31 - t16) : t16;
    const int tid = threadIdx.x, lane = tid & 63, w = tid >> 6;
    const int qs = w & 3, par = w >> 2;
    const int li = lane & 31, hf = lane >> 5;
    const int qw0 = s * 128 + qs * 32;
    const int qrow = qw0 + li;
    const int jmaxw = 2 * s + (qs >> 1);
    const int nst = s + 1;
    const char* KhB = (const char*)(K + (size_t)head * LSEQ * HD);
    const char* VhB = (const char*)(Vt + (size_t)head * HD * LSEQ);

    u16x8 bq[4];
    #pragma unroll
    for (int ks = 0; ks < 4; ++ks)
        bq[ks] = *(const u16x8*)(Q + ((size_t)head * LSEQ + qrow) * HD + ks * 16 + hf * 8);

    int off[4];
    #pragma unroll
    for (int ks = 0; ks < 4; ++ks) {
        const int c = 2 * ks + hf;
        off[ks] = c * 1024 + (((li & 24) | ((li & 7) ^ c)) << 4);
    }

    const int row0 = (tid >> 3) & 31, sch = tid & 7, half = tid >> 8;
    const int wd0 = sch * 1024 + (((row0 & 24) | ((row0 & 7) ^ sch)) << 4);

    u16x8 kr0, kr1, vr0, vr1;
    #define LOADKV(js_) do {                                                              \
        const char* kp_ = KhB + ((size_t)((js_) * 128 + half * 64 + row0)) * 128 + sch * 16; \
        const char* vp_ = VhB + (size_t)row0 * (LSEQ * 2) + ((js_) * 128 + half * 64) * 2 + sch * 16; \
        kr0 = *(const u16x8*)kp_;                                                         \
        kr1 = *(const u16x8*)(kp_ + 32 * 128);                                            \
        vr0 = *(const u16x8*)vp_;                                                         \
        vr1 = *(const u16x8*)(vp_ + (size_t)32 * (LSEQ * 2));                             \
    } while (0)
    #define WRITEKV(b_) do {                                                              \
        char* base_ = LB[b_] + half * 8192;                                               \
        *(u16x8*)(base_ + wd0)               = kr0;                                       \
        *(u16x8*)(base_ + wd0 + 512)         = kr1;                                       \
        *(u16x8*)(base_ + 16384 + wd0)       = vr0;                                       \
        *(u16x8*)(base_ + 16384 + wd0 + 512) = vr1;                                       \
    } while (0)

    float l_i = 0.f;
    f32x16 oA = {}, oB = {};

    LOADKV(0);
    WRITEKV(0);
    __syncthreads();
    for (int js = 0; js < nst; ++js) {
        const int cur = js & 1;
        if (js + 1 < nst) LOADKV(js + 1);
        const int j = 2 * js + par;
        if (j <= jmaxw) {
            const char* Kb = LB[cur] + par * 8192;
            const char* Vb = LB[cur] + 16384 + par * 8192;
            f32x16 sA = {}, sB = {};
            __builtin_amdgcn_s_setprio(1);
            #pragma unroll
            for (int ks = 0; ks < 4; ++ks) {
                const u16x8 ka0 = *(const u16x8*)(Kb + off[ks]);
                const u16x8 ka1 = *(const u16x8*)(Kb + off[ks] + 512);
                sA = mfma32(ka0, bq[ks], sA);
                sB = mfma32(ka1, bq[ks], sB);
            }
            __builtin_amdgcn_s_setprio(0);
            if (j == jmaxw && (j * 64 + 63 > qw0)) {
                const int kbase = j * 64;
                #pragma unroll
                for (int r = 0; r < 16; ++r) {
                    const int kvl = kbase + (r & 3) + 8 * (r >> 2) + 4 * hf;
                    if (kvl > qrow)      sA[r] = -1e30f;
                    if (kvl + 32 > qrow) sB[r] = -1e30f;
                }
            }
            float s0 = 0.f, s1 = 0.f;
            unsigned uA[8], uB[8];
            #pragma unroll
            for (int wd = 0; wd < 8; ++wd) {
                const float a0 = __builtin_amdgcn_exp2f(sA[2 * wd]);
                const float a1 = __builtin_amdgcn_exp2f(sA[2 * wd + 1]);
                const float b0 = __builtin_amdgcn_exp2f(sB[2 * wd]);
                const float b1 = __builtin_amdgcn_exp2f(sB[2 * wd + 1]);
                s0 += a0 + a1; s1 += b0 + b1;
                uA[wd] = cvt_pk_bf16(a0, a1);
                uB[wd] = cvt_pk_bf16(b0, b1);
            }
            l_i += s0 + s1;
            plswap(uA[0], uA[2]); plswap(uA[1], uA[3]);
            plswap(uA[4], uA[6]); plswap(uA[5], uA[7]);
            plswap(uB[0], uB[2]); plswap(uB[1], uB[3]);
            plswap(uB[4], uB[6]); plswap(uB[5], uB[7]);
            const u32x4 wA0 = {uA[0], uA[1], uA[2], uA[3]};
            const u32x4 wA1 = {uA[4], uA[5], uA[6], uA[7]};
            const u32x4 wB0 = {uB[0], uB[1], uB[2], uB[3]};
            const u32x4 wB1 = {uB[4], uB[5], uB[6], uB[7]};
            const u16x8 ap0 = __builtin_bit_cast(u16x8, wA0);
            const u16x8 ap1 = __builtin_bit_cast(u16x8, wA1);
            const u16x8 ap2 = __builtin_bit_cast(u16x8, wB0);
            const u16x8 ap3 = __builtin_bit_cast(u16x8, wB1);
            const u16x8 va0 = *(const u16x8*)(Vb + off[0]);
            const u16x8 va1 = *(const u16x8*)(Vb + off[1]);
            const u16x8 va2 = *(const u16x8*)(Vb + off[2]);
            const u16x8 va3 = *(const u16x8*)(Vb + off[3]);
            const u16x8 vc0 = *(const u16x8*)(Vb + off[0] + 512);
            const u16x8 vc1 = *(const u16x8*)(Vb + off[1] + 512);
            const u16x8 vc2 = *(const u16x8*)(Vb + off[2] + 512);
            const u16x8 vc3 = *(const u16x8*)(Vb + off[3] + 512);
            __builtin_amdgcn_s_setprio(1);
            oA = mfma32(ap0, va0, oA);
            oA = mfma32(ap1, va1, oA);
            oA = mfma32(ap2, va2, oA);
            oA = mfma32(ap3, va3, oA);
            oB = mfma32(ap0, vc0, oB);
            oB = mfma32(ap1, vc1, oB);
            oB = mfma32(ap2, vc2, oB);
            oB = mfma32(ap3, vc3, oB);
            __builtin_amdgcn_s_setprio(0);
        }
        if (js + 1 < nst) WRITEKV(cur ^ 1);
        __syncthreads();
    }
    #undef LOADKV
    #undef WRITEKV
    if (par == 1) {
        float* po = (float*)(LB[0] + qs * 8192);
        #pragma unroll
        for (int r = 0; r < 16; ++r) {
            po[r * 64 + lane]        = oA[r];
            po[(16 + r) * 64 + lane] = oB[r];
        }
        ((float*)LB[1])[qs * 64 + lane] = l_i;
    }
    __syncthreads();
    if (par == 0) {
        const float* po = (const float*)(LB[0] + qs * 8192);
        l_i += ((const float*)LB[1])[qs * 64 + lane];
        #pragma unroll
        for (int r = 0; r < 16; ++r) {
            oA[r] += po[r * 64 + lane];
            oB[r] += po[(16 + r) * 64 + lane];
        }
        const float lt = l_i + __shfl_xor(l_i, 32);
        const float linv = 1.0f / lt;
        #pragma unroll
        for (int r = 0; r < 16; ++r) {
            const int ql = (r & 3) + 8 * (r >> 2) + 4 * hf;
            const float gl = __shfl(linv, ql);
            Y[(size_t)(qw0 + ql) * EMB + head * HD + li]      = f2bf(oA[r] * gl);
            Y[(size_t)(qw0 + ql) * EMB + head * HD + 32 + li] = f2bf(oB[r] * gl);
        }
    }
}

// ---------------- proj GEMM: 64x128 tile, BK=64, swizzled (R19 verbatim) ----------------
__global__ __launch_bounds__(256, 4) void gemm_proj(const unsigned short* __restrict__ A,
                                                    const unsigned short* __restrict__ B,
                                                    float* __restrict__ C) {
    __shared__ unsigned short As[64 * 64];
    __shared__ unsigned short Bs[128 * 64];
    const int d0 = blockIdx.x;
    const int xcd = d0 & 7, i0 = d0 >> 3;
    const int by = xcd * 8 + i0 / 8;
    const int bx = i0 % 8;
    const int tid = threadIdx.x;
    const int lane = tid & 63;
    const int wv = tid >> 6;
    const int wm = wv >> 1, wn = wv & 1;
    const int li = lane & 15, g = lane >> 4;
    const int m0 = by * 64, n0 = bx * 128;
    f32x4 acc[2][4] = {};
    for (int k0 = 0; k0 < EMB; k0 += 64) {
        #pragma unroll
        for (int i = 0; i < 2; ++i) {
            const int o = i * 4096 + tid * 16;
            const int r = o >> 7, sl = (o >> 4) & 7, sc = (sl ^ (r & 7)) << 4;
            gload16((const char*)A + ((size_t)(m0 + r) * EMB + k0) * 2 + sc, (char*)As + o);
        }
        #pragma unroll
        for (int i = 0; i < 4; ++i) {
            const int o = i * 4096 + tid * 16;
            const int r = o >> 7, sl = (o >> 4) & 7, sc = (sl ^ (r & 7)) << 4;
            gload16((const char*)B + ((size_t)(n0 + r) * EMB + k0) * 2 + sc, (char*)Bs + o);
        }
        __syncthreads();
        #pragma unroll
        for (int h = 0; h < 2; ++h) {
            u16x8 af[2], bfr[4];
            #pragma unroll
            for (int mb = 0; mb < 2; ++mb) {
                const int row = wm * 32 + mb * 16 + li;
                const int c = h * 4 + g;
                af[mb] = *(const u16x8*)((const char*)As + row * 128 + ((c ^ (row & 7)) << 4));
            }
            #pragma unroll
            for (int nb = 0; nb < 4; ++nb) {
                const int row = wn * 64 + nb * 16 + li;
                const int c = h * 4 + g;
                bfr[nb] = *(const u16x8*)((const char*)Bs + row * 128 + ((c ^ (row & 7)) << 4));
            }
            #pragma unroll
            for (int mb = 0; mb < 2; ++mb)
                #pragma unroll
                for (int nb = 0; nb < 4; ++nb)
                    acc[mb][nb] = mfma16(af[mb], bfr[nb], acc[mb][nb]);
        }
        __syncthreads();
    }
    for (int mb = 0; mb < 2; ++mb)
        for (int nb = 0; nb < 4; ++nb)
            for (int r = 0; r < 4; ++r) {
                const int m = m0 + wm * 32 + mb * 16 + g * 4 + r;
                const int n = n0 + wn * 64 + nb * 16 + li;
                C[(size_t)m * EMB + n] = acc[mb][nb][r];
            }
}

extern "C" void kernel_launch(void* const* d_in, const int* in_sizes, int n_in,
                              void* d_out, int out_size, void* d_ws, size_t ws_size,
                              hipStream_t stream) {
    const float* x      = (const float*)d_in[0];
    const float* w_attn = (const float*)d_in[1];
    const float* w_proj = (const float*)d_in[2];
    float* out = (float*)d_out;

    unsigned short* ws  = (unsigned short*)d_ws;
    unsigned short* xb  = ws;
    unsigned short* wab = xb + (size_t)LSEQ * EMB;
    unsigned short* wpb = wab + (size_t)3 * EMB * EMB;
    unsigned short* Qb  = wpb + (size_t)EMB * EMB;
    unsigned short* Kb  = Qb + (size_t)LSEQ * EMB;
    unsigned short* Vtb = Kb + (size_t)LSEQ * EMB;
    unsigned short* Yb  = Vtb + (size_t)LSEQ * EMB;

    const int ntot = NXC + NAC + NPC;
    cvt_all<<<(ntot + 255) / 256, 256, 0, stream>>>(x, w_attn, w_proj, xb);
    gemm_qkv<<<dim3(768), 256, 0, stream>>>(xb, wab, Qb, Kb, Vtb);
    attn_fwd<<<dim3(512), 512, 0, stream>>>(Qb, Kb, Vtb, Yb);
    gemm_proj<<<dim3(512), 256, 0, stream>>>(Yb, wpb, out);
}